// Round 1
// baseline (419.083 us; speedup 1.0000x reference)
//
#include <hip/hip_runtime.h>
#include <math.h>

#define NB 32
#define NC 128
#define NT 4096
#define LTOT 982832   // (4096-1)*240 + 32

__device__ __forceinline__ float lrelu_(float x) { return x > 0.0f ? x : 0.1f * x; }

// ---------------- Kernel 1: envelope path ----------------
// envelope[b][t] = sigmoid(env(lrelu(pw2(dw2(lrelu(pw1(dw1(cond))))))))
__global__ __launch_bounds__(256)
void k_env(const float* __restrict__ cond,
           const float* __restrict__ dw1w, const float* __restrict__ dw1b,
           const float* __restrict__ pw1w, const float* __restrict__ pw1b,
           const float* __restrict__ dw2w, const float* __restrict__ dw2b,
           const float* __restrict__ pw2w, const float* __restrict__ pw2b,
           const float* __restrict__ envw, const float* __restrict__ envb,
           float* __restrict__ envout)
{
    __shared__ float Xs[128 * 40];  // cols 0..37 : t = t0-3+j
    __shared__ float H1[128 * 40];  // cols 0..35 : t = t0-2+j (36..39 zero-pad)
    __shared__ float Y1[64 * 36];   // cols 0..35 : t = t0-2+j
    __shared__ float H2[64 * 40];   // cols 0..33 : t = t0-1+j (34..39 zero-pad)
    __shared__ float Y2[32 * 36];   // cols 0..33 : t = t0-1+j

    const int tid = threadIdx.x;
    const int b   = blockIdx.y;
    const int t0  = blockIdx.x * 32;

    // S1: load condition tile (zero-padded in t)
    for (int i = tid; i < 128 * 38; i += 256) {
        int c = i / 38, j = i - c * 38;
        int t = t0 - 3 + j;
        Xs[c * 40 + j] = (t >= 0 && t < NT) ? cond[(b * NC + c) * NT + t] : 0.0f;
    }
    __syncthreads();

    // S2: H1 = dw1(X) + b  (depthwise k3)
    for (int i = tid; i < 128 * 40; i += 256) {
        int c = i / 40, j = i - c * 40;
        float v = 0.0f;
        if (j < 36) {
            v = fmaf(dw1w[c * 3 + 0], Xs[c * 40 + j],
                fmaf(dw1w[c * 3 + 1], Xs[c * 40 + j + 1],
                fmaf(dw1w[c * 3 + 2], Xs[c * 40 + j + 2], dw1b[c])));
        }
        H1[i] = v;
    }
    __syncthreads();

    // S3: Y1 = lrelu(pw1(H1)) : 64 out x 36 cols, K=128 split over 2 thread halves
    {
        const int kp = tid >> 7;
        const int og = (tid >> 3) & 15;
        const int cg = tid & 7;
        const int o0 = og * 4;
        const int c0 = kp * 64;
        float acc[4][5];
        #pragma unroll
        for (int q = 0; q < 4; ++q)
            #pragma unroll
            for (int m = 0; m < 5; ++m) acc[q][m] = 0.0f;
        #pragma unroll 4
        for (int c = 0; c < 64; ++c) {
            const int cc = c0 + c;
            const float w0 = pw1w[(o0 + 0) * 128 + cc];
            const float w1 = pw1w[(o0 + 1) * 128 + cc];
            const float w2 = pw1w[(o0 + 2) * 128 + cc];
            const float w3 = pw1w[(o0 + 3) * 128 + cc];
            float h[5];
            #pragma unroll
            for (int m = 0; m < 5; ++m) h[m] = H1[cc * 40 + cg * 5 + m];
            #pragma unroll
            for (int m = 0; m < 5; ++m) {
                acc[0][m] = fmaf(w0, h[m], acc[0][m]);
                acc[1][m] = fmaf(w1, h[m], acc[1][m]);
                acc[2][m] = fmaf(w2, h[m], acc[2][m]);
                acc[3][m] = fmaf(w3, h[m], acc[3][m]);
            }
        }
        if (kp == 0) {
            #pragma unroll
            for (int q = 0; q < 4; ++q)
                #pragma unroll
                for (int m = 0; m < 5; ++m) {
                    int col = cg * 5 + m;
                    if (col < 36) Y1[(o0 + q) * 36 + col] = acc[q][m];
                }
        }
        __syncthreads();
        if (kp == 1) {
            #pragma unroll
            for (int q = 0; q < 4; ++q)
                #pragma unroll
                for (int m = 0; m < 5; ++m) {
                    int col = cg * 5 + m;
                    if (col < 36) {
                        int tau = t0 - 2 + col;   // halo cols outside [0,T) are conv padding -> 0
                        float v = Y1[(o0 + q) * 36 + col] + acc[q][m] + pw1b[o0 + q];
                        v = lrelu_(v);
                        Y1[(o0 + q) * 36 + col] = (tau >= 0 && tau < NT) ? v : 0.0f;
                    }
                }
        }
        __syncthreads();
    }

    // S4: H2 = dw2(Y1) + b (depthwise k3 over 64 ch)
    for (int i = tid; i < 64 * 40; i += 256) {
        int o = i / 40, j = i - o * 40;
        float v = 0.0f;
        if (j < 34) {
            v = fmaf(dw2w[o * 3 + 0], Y1[o * 36 + j],
                fmaf(dw2w[o * 3 + 1], Y1[o * 36 + j + 1],
                fmaf(dw2w[o * 3 + 2], Y1[o * 36 + j + 2], dw2b[o])));
        }
        H2[i] = v;
    }
    __syncthreads();

    // S5: Y2 = lrelu(pw2(H2)) : 32 out x 34 cols, K=64 split
    {
        const int kp = tid >> 7;
        const int og = (tid >> 3) & 15;
        const int cg = tid & 7;
        const int o0 = og * 2;
        const int c0 = kp * 32;
        float acc[2][5];
        #pragma unroll
        for (int q = 0; q < 2; ++q)
            #pragma unroll
            for (int m = 0; m < 5; ++m) acc[q][m] = 0.0f;
        #pragma unroll 4
        for (int c = 0; c < 32; ++c) {
            const int cc = c0 + c;
            const float w0 = pw2w[(o0 + 0) * 64 + cc];
            const float w1 = pw2w[(o0 + 1) * 64 + cc];
            float h[5];
            #pragma unroll
            for (int m = 0; m < 5; ++m) h[m] = H2[cc * 40 + cg * 5 + m];
            #pragma unroll
            for (int m = 0; m < 5; ++m) {
                acc[0][m] = fmaf(w0, h[m], acc[0][m]);
                acc[1][m] = fmaf(w1, h[m], acc[1][m]);
            }
        }
        if (kp == 0) {
            #pragma unroll
            for (int q = 0; q < 2; ++q)
                #pragma unroll
                for (int m = 0; m < 5; ++m) {
                    int col = cg * 5 + m;
                    if (col < 34) Y2[(o0 + q) * 36 + col] = acc[q][m];
                }
        }
        __syncthreads();
        if (kp == 1) {
            #pragma unroll
            for (int q = 0; q < 2; ++q)
                #pragma unroll
                for (int m = 0; m < 5; ++m) {
                    int col = cg * 5 + m;
                    if (col < 34) {
                        int tau = t0 - 1 + col;
                        float v = Y2[(o0 + q) * 36 + col] + acc[q][m] + pw2b[o0 + q];
                        v = lrelu_(v);
                        Y2[(o0 + q) * 36 + col] = (tau >= 0 && tau < NT) ? v : 0.0f;
                    }
                }
        }
        __syncthreads();
    }

    // S6: envelope = sigmoid(env conv k3 over 32 ch)
    if (tid < 32) {
        const int j = tid;
        float a = envb[0];
        #pragma unroll 4
        for (int c = 0; c < 32; ++c) {
            a = fmaf(envw[c * 3 + 0], Y2[c * 36 + j],
                fmaf(envw[c * 3 + 1], Y2[c * 36 + j + 1],
                fmaf(envw[c * 3 + 2], Y2[c * 36 + j + 2], a)));
        }
        envout[b * NT + t0 + j] = 1.0f / (1.0f + expf(-a));
    }
}

// ---------------- Kernel 2: selection path + top3/softmax ----------------
__global__ __launch_bounds__(256)
void k_sel(const float* __restrict__ cond,
           const float* __restrict__ sdww, const float* __restrict__ sdwb,
           const float* __restrict__ spww, const float* __restrict__ spwb,
           const float* __restrict__ selw, const float* __restrict__ selb,
           float4* __restrict__ selout)
{
    __shared__ float Xs[128 * 40];  // cols 0..35 : t = t0-2+j
    __shared__ float HS[128 * 40];  // cols 0..33 : t = t0-1+j (34..39 zero)
    __shared__ float Ss[64 * 36];   // cols 0..33 : t = t0-1+j
    __shared__ float Lg[16 * 32];   // logits

    const int tid = threadIdx.x;
    const int b   = blockIdx.y;
    const int t0  = blockIdx.x * 32;

    for (int i = tid; i < 128 * 36; i += 256) {
        int c = i / 36, j = i - c * 36;
        int t = t0 - 2 + j;
        Xs[c * 40 + j] = (t >= 0 && t < NT) ? cond[(b * NC + c) * NT + t] : 0.0f;
    }
    __syncthreads();

    for (int i = tid; i < 128 * 40; i += 256) {
        int c = i / 40, j = i - c * 40;
        float v = 0.0f;
        if (j < 34) {
            v = fmaf(sdww[c * 3 + 0], Xs[c * 40 + j],
                fmaf(sdww[c * 3 + 1], Xs[c * 40 + j + 1],
                fmaf(sdww[c * 3 + 2], Xs[c * 40 + j + 2], sdwb[c])));
        }
        HS[i] = v;
    }
    __syncthreads();

    // S = lrelu(spw(HS)) : 64 x 34, K=128 split
    {
        const int kp = tid >> 7;
        const int og = (tid >> 3) & 15;
        const int cg = tid & 7;
        const int o0 = og * 4;
        const int c0 = kp * 64;
        float acc[4][5];
        #pragma unroll
        for (int q = 0; q < 4; ++q)
            #pragma unroll
            for (int m = 0; m < 5; ++m) acc[q][m] = 0.0f;
        #pragma unroll 4
        for (int c = 0; c < 64; ++c) {
            const int cc = c0 + c;
            const float w0 = spww[(o0 + 0) * 128 + cc];
            const float w1 = spww[(o0 + 1) * 128 + cc];
            const float w2 = spww[(o0 + 2) * 128 + cc];
            const float w3 = spww[(o0 + 3) * 128 + cc];
            float h[5];
            #pragma unroll
            for (int m = 0; m < 5; ++m) h[m] = HS[cc * 40 + cg * 5 + m];
            #pragma unroll
            for (int m = 0; m < 5; ++m) {
                acc[0][m] = fmaf(w0, h[m], acc[0][m]);
                acc[1][m] = fmaf(w1, h[m], acc[1][m]);
                acc[2][m] = fmaf(w2, h[m], acc[2][m]);
                acc[3][m] = fmaf(w3, h[m], acc[3][m]);
            }
        }
        if (kp == 0) {
            #pragma unroll
            for (int q = 0; q < 4; ++q)
                #pragma unroll
                for (int m = 0; m < 5; ++m) {
                    int col = cg * 5 + m;
                    if (col < 34) Ss[(o0 + q) * 36 + col] = acc[q][m];
                }
        }
        __syncthreads();
        if (kp == 1) {
            #pragma unroll
            for (int q = 0; q < 4; ++q)
                #pragma unroll
                for (int m = 0; m < 5; ++m) {
                    int col = cg * 5 + m;
                    if (col < 34) {
                        int tau = t0 - 1 + col;
                        float v = Ss[(o0 + q) * 36 + col] + acc[q][m] + spwb[o0 + q];
                        v = lrelu_(v);
                        Ss[(o0 + q) * 36 + col] = (tau >= 0 && tau < NT) ? v : 0.0f;
                    }
                }
        }
        __syncthreads();
    }

    // logits = sel(S) : 16 out x 32 cols, k3 over 64 ch, K split
    {
        const int kp = tid >> 7;
        const int o  = (tid >> 3) & 15;
        const int cg = tid & 7;
        const int c0 = kp * 32;
        float acc[4] = {0.0f, 0.0f, 0.0f, 0.0f};
        #pragma unroll 4
        for (int c = 0; c < 32; ++c) {
            const int cc = c0 + c;
            const float w0 = selw[(o * 64 + cc) * 3 + 0];
            const float w1 = selw[(o * 64 + cc) * 3 + 1];
            const float w2 = selw[(o * 64 + cc) * 3 + 2];
            float sv[6];
            #pragma unroll
            for (int m = 0; m < 6; ++m) sv[m] = Ss[cc * 36 + cg * 4 + m];
            #pragma unroll
            for (int m = 0; m < 4; ++m)
                acc[m] = fmaf(w0, sv[m], fmaf(w1, sv[m + 1], fmaf(w2, sv[m + 2], acc[m])));
        }
        if (kp == 0) {
            #pragma unroll
            for (int m = 0; m < 4; ++m) Lg[o * 32 + cg * 4 + m] = acc[m];
        }
        __syncthreads();
        if (kp == 1) {
            #pragma unroll
            for (int m = 0; m < 4; ++m)
                Lg[o * 32 + cg * 4 + m] += acc[m] + selb[o];
        }
        __syncthreads();
    }

    // top-3 + softmax, one thread per time step
    if (tid < 32) {
        const int jt = tid;
        float v[16];
        #pragma unroll
        for (int a = 0; a < 16; ++a) v[a] = Lg[a * 32 + jt];
        int i0 = 0; float m0 = v[0];
        #pragma unroll
        for (int a = 1; a < 16; ++a) if (v[a] > m0) { m0 = v[a]; i0 = a; }
        v[i0] = -INFINITY;
        int i1 = 0; float m1 = v[0];
        #pragma unroll
        for (int a = 1; a < 16; ++a) if (v[a] > m1) { m1 = v[a]; i1 = a; }
        v[i1] = -INFINITY;
        int i2 = 0; float m2 = v[0];
        #pragma unroll
        for (int a = 1; a < 16; ++a) if (v[a] > m2) { m2 = v[a]; i2 = a; }
        float e1 = expf(m1 - m0), e2 = expf(m2 - m0);
        float s = 1.0f + e1 + e2;
        float4 r;
        r.x = 1.0f / s;
        r.y = e1 / s;
        r.z = e2 / s;
        r.w = (float)(i0 | (i1 << 4) | (i2 << 8));
        selout[b * NT + t0 + jt] = r;
    }
}

// ---------------- Kernel 3: placement * smoothed upsampled envelope ----------------
// One wave per frame: 240 output samples (32 active, 208 zeros), float4 stores.
__global__ __launch_bounds__(256)
void k_out(const float* __restrict__ env,
           const float4* __restrict__ sel,
           const float* __restrict__ atoms,
           const float* __restrict__ smw,
           float* __restrict__ out)
{
    __shared__ float at[512];
    const int tid = threadIdx.x;
    for (int i = tid; i < 512; i += 256) at[i] = atoms[i];
    __syncthreads();

    const int fid  = blockIdx.x * 4 + (tid >> 6);
    const int b    = fid >> 12;
    const int t    = fid & 4095;
    const int lane = tid & 63;
    const int base = b * LTOT + t * 240;

    if (lane < 8) {
        const float4 sv = sel[fid];
        const int p  = (int)(sv.w + 0.5f);
        const int i0 = p & 15, i1 = (p >> 4) & 15, i2 = (p >> 8) & 15;
        const int j0 = lane * 4;
        float r[4];
        #pragma unroll
        for (int q = 0; q < 4; ++q) {
            const int j = j0 + q;
            const float fv = sv.x * at[i0 * 32 + j] + sv.y * at[i1 * 32 + j] + sv.z * at[i2 * 32 + j];
            const int ip = t * 240 + j;
            float es = 0.0f;
            #pragma unroll
            for (int d = -3; d <= 3; ++d) {
                const int ii = ip + d;
                if (ii >= 0 && ii < LTOT) {
                    // exact match to np: floor(i * (4096/982832)) in double
                    const int nn = (int)((double)ii * (4096.0 / 982832.0));
                    es = fmaf(smw[d + 3], env[b * NT + nn], es);
                }
            }
            r[q] = fv * es;
        }
        *(float4*)(out + base + j0) = make_float4(r[0], r[1], r[2], r[3]);
    } else if (lane < 60) {
        const int idx = t * 240 + lane * 4;
        if (idx + 4 <= LTOT) {
            *(float4*)(out + base + lane * 4) = make_float4(0.0f, 0.0f, 0.0f, 0.0f);
        }
    }
}

extern "C" void kernel_launch(void* const* d_in, const int* in_sizes, int n_in,
                              void* d_out, int out_size, void* d_ws, size_t ws_size,
                              hipStream_t stream)
{
    const float* cond  = (const float*)d_in[0];
    // d_in[1] = audio_length (constant 982832, baked in)
    const float* dw1w  = (const float*)d_in[2];
    const float* dw1b  = (const float*)d_in[3];
    const float* pw1w  = (const float*)d_in[4];
    const float* pw1b  = (const float*)d_in[5];
    const float* dw2w  = (const float*)d_in[6];
    const float* dw2b  = (const float*)d_in[7];
    const float* pw2w  = (const float*)d_in[8];
    const float* pw2b  = (const float*)d_in[9];
    const float* envw  = (const float*)d_in[10];
    const float* envb  = (const float*)d_in[11];
    const float* smw   = (const float*)d_in[12];
    const float* sdww  = (const float*)d_in[13];
    const float* sdwb  = (const float*)d_in[14];
    const float* spww  = (const float*)d_in[15];
    const float* spwb  = (const float*)d_in[16];
    const float* selw  = (const float*)d_in[17];
    const float* selb  = (const float*)d_in[18];
    const float* atoms = (const float*)d_in[19];
    float* out = (float*)d_out;

    float*  envbuf = (float*)d_ws;
    float4* selbuf = (float4*)((char*)d_ws + (size_t)NB * NT * sizeof(float));

    dim3 g1(NT / 32, NB);
    k_env<<<g1, 256, 0, stream>>>(cond, dw1w, dw1b, pw1w, pw1b, dw2w, dw2b,
                                  pw2w, pw2b, envw, envb, envbuf);
    k_sel<<<g1, 256, 0, stream>>>(cond, sdww, sdwb, spww, spwb, selw, selb, selbuf);
    k_out<<<(NB * NT) / 4, 256, 0, stream>>>(envbuf, selbuf, atoms, smw, out);
}